// Round 8
// baseline (969.076 us; speedup 1.0000x reference)
//
#include <hip/hip_runtime.h>

#define Bb 64
#define Tt 12
#define Nn 512
#define Dd 2
#define G3 192
#define Hh 12
#define NSUB 16

typedef float f32x4 __attribute__((ext_vector_type(4)));
typedef _Float16 f16;
typedef _Float16 f16x8 __attribute__((ext_vector_type(8)));

// XOR swizzle for 64x64 fp32 LDS tile (row stride 256B), 16B-granular.
__device__ __forceinline__ int swz4(int row, int bo) {
  return row * 256 + (bo ^ ((row & 7) << 4));
}

// Hierarchical grid barrier: 16 sub-counters (32 arrivals each) -> root ->
// generation flag. Agent-scope acq/rel atomics provide the cross-XCD L2
// writeback/invalidate per the HIP memory model. clock64 escape anti-hang.
__device__ __forceinline__ void gridbar(int* bar) {
  __syncthreads();
  if (threadIdx.x == 0) {
    int* subs = bar;                      // sub i at bar[i*32] (128B apart)
    int* root = bar + NSUB * 32;
    int* gen = bar + NSUB * 32 + 32;
    const int g = __hip_atomic_load(gen, __ATOMIC_RELAXED, __HIP_MEMORY_SCOPE_AGENT);
    const int sub = (int)(blockIdx.x & (NSUB - 1));
    const int a = __hip_atomic_fetch_add(&subs[sub * 32], 1, __ATOMIC_ACQ_REL,
                                         __HIP_MEMORY_SCOPE_AGENT);
    if (a == (Nn / NSUB) - 1) {
      __hip_atomic_store(&subs[sub * 32], 0, __ATOMIC_RELAXED, __HIP_MEMORY_SCOPE_AGENT);
      const int r = __hip_atomic_fetch_add(root, 1, __ATOMIC_ACQ_REL,
                                           __HIP_MEMORY_SCOPE_AGENT);
      if (r == NSUB - 1) {
        __hip_atomic_store(root, 0, __ATOMIC_RELAXED, __HIP_MEMORY_SCOPE_AGENT);
        __hip_atomic_fetch_add(gen, 1, __ATOMIC_RELEASE, __HIP_MEMORY_SCOPE_AGENT);
      }
    }
    const long long t0 = clock64();
    while (__hip_atomic_load(gen, __ATOMIC_RELAXED, __HIP_MEMORY_SCOPE_AGENT) == g) {
      __builtin_amdgcn_s_sleep(16);
      if (clock64() - t0 > 200000000LL) break;   // ~80ms escape: no hang
    }
    (void)__hip_atomic_load(gen, __ATOMIC_ACQUIRE, __HIP_MEMORY_SCOPE_AGENT);
  }
  __syncthreads();
}

// ---------------------------------------------------------------------------
// One persistent kernel: init phase, then 12 x { agg ; bar ; step ; bar }.
// 512 blocks x 256 thr, 77824B LDS -> exactly 2 blocks/CU -> all co-resident.
// ---------------------------------------------------------------------------
__global__ __launch_bounds__(256, 2) void mpnn_persist(
    const float* __restrict__ xin, const float* __restrict__ h0,
    const float* __restrict__ adj, const float* __restrict__ W_msg,
    const float* __restrict__ W_ih, const float* __restrict__ W_hh,
    const float* __restrict__ b_ih, const float* __restrict__ b_hh,
    const float* __restrict__ b_msg, const float* __restrict__ W_out,
    const float* __restrict__ b_out, float* __restrict__ out,
    float* __restrict__ h_ws, float* __restrict__ s_buf,
    f16* __restrict__ g_atf, f16* __restrict__ g_w, float* __restrict__ g_f,
    float* __restrict__ g_rowsum, int* __restrict__ bar) {
  __shared__ uint4 sBlob[3840];   // 61440B: f16 W frags + fp32 extras
  __shared__ float m_lds[4096];   // swz4 64x64 fp32
  const f16* sBih = (const f16*)sBlob;
  const f16* sBhh = sBih + 12288;
  const f16* sBmsg = sBih + 24576;
  const float* sF = (const float*)(sBih + 28672);
  const float* sWx = sF;
  const float* s_bih = sF + 384;
  const float* s_bhh = sF + 576;
  const float* s_bmsg = sF + 768;

  const int bx = blockIdx.x, tid = threadIdx.x, l = tid & 63, wt = tid >> 6;

  // ================= init phase =================
  {
    // every block: h0 -> h_ws for its node
    const float4* src = (const float4*)(h0 + (size_t)bx * 4096);
    float4* dst = (float4*)(h_ws + (size_t)bx * 4096);
    for (int i = tid; i < 1024; i += 256) dst[i] = src[i];
  }
  if (bx < 32) {
    const int it = bx;
    for (int kt = wt; kt < 16; kt += 4) {
      const int i = (it << 4) + (l & 15);
      const int j0 = (kt << 5) + ((l >> 4) << 3);
      f16* dhi = g_atf + ((it * 16 + kt) * 2 + 0) * 512 + l * 8;
      f16* dlo = g_atf + ((it * 16 + kt) * 2 + 1) * 512 + l * 8;
#pragma unroll
      for (int e = 0; e < 8; ++e) {
        float a = adj[(j0 + e) * Nn + i];
        a = a > 0.f ? a : 0.f;
        const f16 h = (f16)a;
        dhi[e] = h;
        dlo[e] = (f16)(a - (float)h);
      }
    }
    {  // rowsum[i] = sum_j adjpos[j][i]
      const int i = (it << 4) + (tid >> 4);
      float rs = 0.f;
      for (int j = (tid & 15); j < Nn; j += 16) {
        const float a = adj[j * Nn + i];
        rs += (a > 0.f ? a : 0.f);
      }
      for (int off = 8; off; off >>= 1) rs += __shfl_down(rs, off, 16);
      if ((tid & 15) == 0) g_rowsum[i] = rs;
    }
  } else if (bx == 40) {
    // weight frag packing: frag (nt,kt): lane l elem j = W[nt*16+(l&15)][kt*32+8*(l>>4)+j]
    for (int tile = wt; tile < 24; tile += 4) {
      const int nt = tile >> 1, kt = tile & 1;
      const int wrow = nt * 16 + (l & 15);
      const int kc = kt * 32 + ((l >> 4) << 3);
      const float* s2 = W_ih + wrow * 66 + kc;
      const float* s1 = W_hh + wrow * 64 + kc;
#pragma unroll
      for (int j = 0; j < 8; ++j) {
        g_w[tile * 512 + l * 8 + j] = (f16)s2[j];
        g_w[12288 + tile * 512 + l * 8 + j] = (f16)s1[j];
      }
    }
    for (int tile = wt; tile < 8; tile += 4) {
      const int nt = tile >> 1, kt = tile & 1;
      const int wrow = nt * 16 + (l & 15);
      const int kc = kt * 32 + ((l >> 4) << 3);
      const float* s1 = W_msg + wrow * 64 + kc;
#pragma unroll
      for (int j = 0; j < 8; ++j) g_w[24576 + tile * 512 + l * 8 + j] = (f16)s1[j];
    }
    if (tid < G3) {
      g_f[tid * 2] = W_ih[tid * 66 + 64];
      g_f[tid * 2 + 1] = W_ih[tid * 66 + 65];
      g_f[384 + tid] = b_ih[tid];
      g_f[576 + tid] = b_hh[tid];
    }
    if (tid < 64) g_f[768 + tid] = b_msg[tid];
  }
  gridbar(bar);

  // stage weight blob to LDS ONCE (first cross-wave use is after next gridbar)
  {
    const uint4* g_blob = (const uint4*)g_w;
    for (int i = tid; i < 3840; i += 256) sBlob[i] = g_blob[i];
  }

  // ================= time loop =================
  const int n = bx;
  const int ar = wt * 16 + (l & 15);      // A/C row (= batch b for step)
  const int kc = (l >> 4) << 3;           // A-frag k base

#pragma unroll 1
  for (int t = 0; t < Tt; ++t) {
    // ---- agg phase: block (bi=bx>>6, bc=bx&63), no LDS ----
    {
      const int bi = bx >> 6, bc = bx & 63;
      const int c0 = bc << 6;
      const int it = (bi << 2) + wt;
      const int cl = l & 15;
      const int jk = (l >> 4) << 3;
      const float* hp = h_ws + (size_t)jk * 4096 + c0 + cl;
      const f16* ap = g_atf + (it * 16) * 2 * 512 + l * 8;

      f32x4 acc[4];
#pragma unroll
      for (int nt = 0; nt < 4; ++nt) acc[nt] = (f32x4){0.f, 0.f, 0.f, 0.f};

#pragma unroll 2
      for (int kt = 0; kt < 16; ++kt) {
        float v[32];
#pragma unroll
        for (int nt = 0; nt < 4; ++nt)
#pragma unroll
          for (int e = 0; e < 8; ++e)
            v[nt * 8 + e] = hp[(size_t)(kt * 32 + e) * 4096 + nt * 16];

        const f16x8 ahi = *(const f16x8*)(ap + (kt * 2 + 0) * 512);
        const f16x8 alo = *(const f16x8*)(ap + (kt * 2 + 1) * 512);
#pragma unroll
        for (int nt = 0; nt < 4; ++nt) {
          f16x8 bhi, blo;
#pragma unroll
          for (int e = 0; e < 8; ++e) {
            const float x = v[nt * 8 + e];
            const f16 h = (f16)x;
            bhi[e] = h;
            blo[e] = (f16)(x - (float)h);
          }
          acc[nt] = __builtin_amdgcn_mfma_f32_16x16x32_f16(ahi, bhi, acc[nt], 0, 0, 0);
          acc[nt] = __builtin_amdgcn_mfma_f32_16x16x32_f16(alo, bhi, acc[nt], 0, 0, 0);
          acc[nt] = __builtin_amdgcn_mfma_f32_16x16x32_f16(ahi, blo, acc[nt], 0, 0, 0);
        }
      }
      const int ib = (it << 4) + ((l >> 4) << 2);
#pragma unroll
      for (int nt = 0; nt < 4; ++nt) {
        const int col = c0 + (nt << 4) + cl;
#pragma unroll
        for (int g = 0; g < 4; ++g)
          s_buf[(ib + g) * 4096 + col] = acc[nt][g];
      }
    }
    gridbar(bar);   // s visible to all; also publishes sBlob to all waves

    // ---- step phase: block = node n ----
    {
      float x0[4], x1[4];
#pragma unroll
      for (int g = 0; g < 4; ++g) {
        const int brow = wt * 16 + ((l >> 4) << 2) + g;
        const float2 xv = *(const float2*)(xin + ((brow * Tt + t) * Nn + n) * Dd);
        x0[g] = xv.x;
        x1[g] = xv.y;
      }
      const float rsum = g_rowsum[n];
      const float* hrow = h_ws + (size_t)n * 4096;
      const float* srow = s_buf + (size_t)n * 4096;

      f16x8 shi0, slo0, shi1, slo1;
      {
        const float4 q0 = *(const float4*)(srow + ar * 64 + kc);
        const float4 q1 = *(const float4*)(srow + ar * 64 + kc + 4);
        const float4 q2 = *(const float4*)(srow + ar * 64 + 32 + kc);
        const float4 q3 = *(const float4*)(srow + ar * 64 + 36 + kc);
        const float v[16] = {q0.x, q0.y, q0.z, q0.w, q1.x, q1.y, q1.z, q1.w,
                             q2.x, q2.y, q2.z, q2.w, q3.x, q3.y, q3.z, q3.w};
#pragma unroll
        for (int j = 0; j < 8; ++j) {
          f16 h = (f16)v[j];       shi0[j] = h; slo0[j] = (f16)(v[j] - (float)h);
          f16 g = (f16)v[8 + j];   shi1[j] = g; slo1[j] = (f16)(v[8 + j] - (float)g);
        }
      }
      f16x8 ahi0, alo0, ahi1, alo1;
      {
        const float4 q0 = *(const float4*)(hrow + ar * 64 + kc);
        const float4 q1 = *(const float4*)(hrow + ar * 64 + kc + 4);
        const float4 q2 = *(const float4*)(hrow + ar * 64 + 32 + kc);
        const float4 q3 = *(const float4*)(hrow + ar * 64 + 36 + kc);
        const float v[16] = {q0.x, q0.y, q0.z, q0.w, q1.x, q1.y, q1.z, q1.w,
                             q2.x, q2.y, q2.z, q2.w, q3.x, q3.y, q3.z, q3.w};
#pragma unroll
        for (int j = 0; j < 8; ++j) {
          f16 h = (f16)v[j];       ahi0[j] = h; alo0[j] = (f16)(v[j] - (float)h);
          f16 g = (f16)v[8 + j];   ahi1[j] = g; alo1[j] = (f16)(v[8 + j] - (float)g);
        }
      }
      float hreg[4][4];
#pragma unroll
      for (int ct = 0; ct < 4; ++ct)
#pragma unroll
        for (int g = 0; g < 4; ++g) {
          const int row = wt * 16 + ((l >> 4) << 2) + g;
          hreg[ct][g] = hrow[row * 64 + ct * 16 + (l & 15)];
        }

      // m = s @ W_msg^T + rsum*b_msg -> m_lds (own-wave rows)
      {
        f32x4 cm[4];
#pragma unroll
        for (int nt = 0; nt < 4; ++nt) {
          cm[nt] = (f32x4){0.f, 0.f, 0.f, 0.f};
          const f16x8 b0 = *(const f16x8*)(sBmsg + (nt * 2 + 0) * 512 + l * 8);
          const f16x8 b1 = *(const f16x8*)(sBmsg + (nt * 2 + 1) * 512 + l * 8);
          cm[nt] = __builtin_amdgcn_mfma_f32_16x16x32_f16(shi0, b0, cm[nt], 0, 0, 0);
          cm[nt] = __builtin_amdgcn_mfma_f32_16x16x32_f16(slo0, b0, cm[nt], 0, 0, 0);
          cm[nt] = __builtin_amdgcn_mfma_f32_16x16x32_f16(shi1, b1, cm[nt], 0, 0, 0);
          cm[nt] = __builtin_amdgcn_mfma_f32_16x16x32_f16(slo1, b1, cm[nt], 0, 0, 0);
        }
#pragma unroll
        for (int nt = 0; nt < 4; ++nt) {
          const int col = nt * 16 + (l & 15);
          const float bm = rsum * s_bmsg[col];
#pragma unroll
          for (int g = 0; g < 4; ++g) {
            const int row = wt * 16 + ((l >> 4) << 2) + g;
            *(float*)((char*)m_lds + swz4(row, col * 4)) = cm[nt][g] + bm;
          }
        }
      }
      f16x8 mhi0, mlo0, mhi1, mlo1;
      {
        const float4 p0 = *(const float4*)((const char*)m_lds + swz4(ar, kc * 4));
        const float4 p1 = *(const float4*)((const char*)m_lds + swz4(ar, kc * 4 + 16));
        const float4 p2 = *(const float4*)((const char*)m_lds + swz4(ar, 128 + kc * 4));
        const float4 p3 = *(const float4*)((const char*)m_lds + swz4(ar, 128 + kc * 4 + 16));
        const float v[16] = {p0.x, p0.y, p0.z, p0.w, p1.x, p1.y, p1.z, p1.w,
                             p2.x, p2.y, p2.z, p2.w, p3.x, p3.y, p3.z, p3.w};
#pragma unroll
        for (int j = 0; j < 8; ++j) {
          f16 h = (f16)v[j];       mhi0[j] = h; mlo0[j] = (f16)(v[j] - (float)h);
          f16 g = (f16)v[8 + j];   mlo1[j] = 0; mhi1[j] = g; mlo1[j] = (f16)(v[8 + j] - (float)g);
        }
      }

      f32x4 cgi[12], cgh[12];
#pragma unroll
      for (int nt = 0; nt < 12; ++nt) {
        cgi[nt] = (f32x4){0.f, 0.f, 0.f, 0.f};
        cgh[nt] = (f32x4){0.f, 0.f, 0.f, 0.f};
      }
#pragma unroll
      for (int nt = 0; nt < 12; ++nt) {
        const f16x8 bh0 = *(const f16x8*)(sBhh + (nt * 2 + 0) * 512 + l * 8);
        const f16x8 bh1 = *(const f16x8*)(sBhh + (nt * 2 + 1) * 512 + l * 8);
        cgh[nt] = __builtin_amdgcn_mfma_f32_16x16x32_f16(ahi0, bh0, cgh[nt], 0, 0, 0);
        cgh[nt] = __builtin_amdgcn_mfma_f32_16x16x32_f16(alo0, bh0, cgh[nt], 0, 0, 0);
        cgh[nt] = __builtin_amdgcn_mfma_f32_16x16x32_f16(ahi1, bh1, cgh[nt], 0, 0, 0);
        cgh[nt] = __builtin_amdgcn_mfma_f32_16x16x32_f16(alo1, bh1, cgh[nt], 0, 0, 0);
        const f16x8 bi0 = *(const f16x8*)(sBih + (nt * 2 + 0) * 512 + l * 8);
        const f16x8 bi1 = *(const f16x8*)(sBih + (nt * 2 + 1) * 512 + l * 8);
        cgi[nt] = __builtin_amdgcn_mfma_f32_16x16x32_f16(mhi0, bi0, cgi[nt], 0, 0, 0);
        cgi[nt] = __builtin_amdgcn_mfma_f32_16x16x32_f16(mlo0, bi0, cgi[nt], 0, 0, 0);
        cgi[nt] = __builtin_amdgcn_mfma_f32_16x16x32_f16(mhi1, bi1, cgi[nt], 0, 0, 0);
        cgi[nt] = __builtin_amdgcn_mfma_f32_16x16x32_f16(mlo1, bi1, cgi[nt], 0, 0, 0);
      }

#pragma unroll
      for (int ct = 0; ct < 4; ++ct) {
        const int colr = ct * 16 + (l & 15);
        const float wr0 = sWx[colr * 2], wr1 = sWx[colr * 2 + 1];
        const float wz0 = sWx[(colr + 64) * 2], wz1 = sWx[(colr + 64) * 2 + 1];
        const float wn0 = sWx[(colr + 128) * 2], wn1 = sWx[(colr + 128) * 2 + 1];
        const float bir = s_bih[colr], biz = s_bih[colr + 64], bin_ = s_bih[colr + 128];
        const float bhr = s_bhh[colr], bhz = s_bhh[colr + 64], bhn = s_bhh[colr + 128];
#pragma unroll
        for (int g = 0; g < 4; ++g) {
          const int row = wt * 16 + ((l >> 4) << 2) + g;
          const float gir = cgi[ct][g] + x0[g] * wr0 + x1[g] * wr1 + bir;
          const float giz = cgi[ct + 4][g] + x0[g] * wz0 + x1[g] * wz1 + biz;
          const float gin = cgi[ct + 8][g] + x0[g] * wn0 + x1[g] * wn1 + bin_;
          const float ghr = cgh[ct][g] + bhr;
          const float ghz = cgh[ct + 4][g] + bhz;
          const float ghn = cgh[ct + 8][g] + bhn;
          const float rg = 1.f / (1.f + __expf(-(gir + ghr)));
          const float zg = 1.f / (1.f + __expf(-(giz + ghz)));
          const float pa = gin + rg * ghn;
          const float e2 = __expf(-2.f * fabsf(pa));
          float th = (1.f - e2) / (1.f + e2);
          th = copysignf(th, pa);
          const float hn = (1.f - zg) * th + zg * hreg[ct][g];
          if (t < Tt - 1) {
            h_ws[(size_t)n * 4096 + row * 64 + colr] = hn;
          } else {
            *(float*)((char*)m_lds + swz4(row, colr * 4)) = hn;
          }
        }
      }

      if (t == Tt - 1) {
        f16x8 ohi0, olo0, ohi1, olo1;
        {
          const float4 p0 = *(const float4*)((const char*)m_lds + swz4(ar, kc * 4));
          const float4 p1 = *(const float4*)((const char*)m_lds + swz4(ar, kc * 4 + 16));
          const float4 p2 = *(const float4*)((const char*)m_lds + swz4(ar, 128 + kc * 4));
          const float4 p3 = *(const float4*)((const char*)m_lds + swz4(ar, 128 + kc * 4 + 16));
          const float v[16] = {p0.x, p0.y, p0.z, p0.w, p1.x, p1.y, p1.z, p1.w,
                               p2.x, p2.y, p2.z, p2.w, p3.x, p3.y, p3.z, p3.w};
#pragma unroll
          for (int j = 0; j < 8; ++j) {
            f16 h = (f16)v[j];       ohi0[j] = h; olo0[j] = (f16)(v[j] - (float)h);
            f16 g = (f16)v[8 + j];   ohi1[j] = g; olo1[j] = (f16)(v[8 + j] - (float)g);
          }
        }
        const int o = l & 15;
        f16x8 wo0 = {0, 0, 0, 0, 0, 0, 0, 0}, wo1 = {0, 0, 0, 0, 0, 0, 0, 0};
        if (o < Hh) {
          const float* wr_ = W_out + o * 64 + kc;
          const float4 w0 = *(const float4*)(wr_);
          const float4 w1 = *(const float4*)(wr_ + 4);
          const float4 w2 = *(const float4*)(wr_ + 32);
          const float4 w3 = *(const float4*)(wr_ + 36);
          wo0[0] = (f16)w0.x; wo0[1] = (f16)w0.y; wo0[2] = (f16)w0.z; wo0[3] = (f16)w0.w;
          wo0[4] = (f16)w1.x; wo0[5] = (f16)w1.y; wo0[6] = (f16)w1.z; wo0[7] = (f16)w1.w;
          wo1[0] = (f16)w2.x; wo1[1] = (f16)w2.y; wo1[2] = (f16)w2.z; wo1[3] = (f16)w2.w;
          wo1[4] = (f16)w3.x; wo1[5] = (f16)w3.y; wo1[6] = (f16)w3.z; wo1[7] = (f16)w3.w;
        }
        f32x4 c = {0.f, 0.f, 0.f, 0.f};
        c = __builtin_amdgcn_mfma_f32_16x16x32_f16(ohi0, wo0, c, 0, 0, 0);
        c = __builtin_amdgcn_mfma_f32_16x16x32_f16(olo0, wo0, c, 0, 0, 0);
        c = __builtin_amdgcn_mfma_f32_16x16x32_f16(ohi1, wo1, c, 0, 0, 0);
        c = __builtin_amdgcn_mfma_f32_16x16x32_f16(olo1, wo1, c, 0, 0, 0);
        if (o < Hh) {
          const float bo_ = b_out[o];
#pragma unroll
          for (int g = 0; g < 4; ++g) {
            const int b = wt * 16 + ((l >> 4) << 2) + g;
            out[(b * Hh + o) * Nn + n] = c[g] + bo_;
          }
        }
      } else {
        gridbar(bar);   // h(t+1) visible to all agg blocks
      }
    }
  }
}

extern "C" void kernel_launch(void* const* d_in, const int* in_sizes, int n_in,
                              void* d_out, int out_size, void* d_ws, size_t ws_size,
                              hipStream_t stream) {
  const float* xin = (const float*)d_in[0];
  const float* h0 = (const float*)d_in[1];
  const float* adj = (const float*)d_in[2];
  const float* W_msg = (const float*)d_in[3];
  const float* b_msg = (const float*)d_in[4];
  const float* W_ih = (const float*)d_in[5];
  const float* W_hh = (const float*)d_in[6];
  const float* b_ih = (const float*)d_in[7];
  const float* b_hh = (const float*)d_in[8];
  const float* W_out = (const float*)d_in[9];
  const float* b_out = (const float*)d_in[10];
  float* out = (float*)d_out;

  // ws: [0,8M) h fp32 | [8M,16M) s fp32 | [16M,17M) g_atf f16 |
  //     17M: g_w 57344B + g_f 3328B (pad to 61440) | +61440 rowsum 2KB |
  //     +65536 barrier state 4KB
  char* ws = (char*)d_ws;
  float* h_ws = (float*)ws;
  float* s_buf = (float*)(ws + (8u << 20));
  f16* g_atf = (f16*)(ws + (16u << 20));
  char* base = ws + (17u << 20);
  f16* g_w = (f16*)base;
  float* g_f = (float*)(base + 57344);
  float* g_rowsum = (float*)(base + 61440);
  int* bar = (int*)(base + 65536);

  hipMemsetAsync(bar, 0, 4096, stream);
  mpnn_persist<<<Nn, 256, 0, stream>>>(xin, h0, adj, W_msg, W_ih, W_hh, b_ih,
                                       b_hh, b_msg, W_out, b_out, out, h_ws,
                                       s_buf, g_atf, g_w, g_f, g_rowsum, bar);
}